// Round 1
// baseline (47.721 us; speedup 1.0000x reference)
//
#include <hip/hip_runtime.h>
#include <math.h>

#define NB 32
#define NJ 64
#define NC 7
#define NH 128
#define NW 128
#define HW (NH*NW)
#define SMOOTHING 0.1f

__global__ __launch_bounds__(256) void labelloss_kernel(
    const float* __restrict__ pred,
    const float* __restrict__ gt,
    const float* __restrict__ heatmap,
    float* __restrict__ out)
{
    const int bj = blockIdx.x;          // b*NJ + j
    const int b  = bj >> 6;
    const int j  = bj & 63;
    const float4* __restrict__ hm4 = (const float4*)(heatmap + (size_t)bj * HW);

    const int t = threadIdx.x;
    float best    = -INFINITY;
    int   bestIdx = HW;                 // sentinel > any real index

    // 16384 floats = 4096 float4; 256 threads x 16 iters, coalesced
    #pragma unroll
    for (int i = 0; i < 16; ++i) {
        const int i4 = t + (i << 8);
        const float4 v = hm4[i4];
        const int base = i4 << 2;
        if (v.x > best || (v.x == best && base     < bestIdx)) { best = v.x; bestIdx = base;     }
        if (v.y > best || (v.y == best && base + 1 < bestIdx)) { best = v.y; bestIdx = base + 1; }
        if (v.z > best || (v.z == best && base + 2 < bestIdx)) { best = v.z; bestIdx = base + 2; }
        if (v.w > best || (v.w == best && base + 3 < bestIdx)) { best = v.w; bestIdx = base + 3; }
    }

    // wave-64 butterfly-style down reduction (max, tie -> min index)
    #pragma unroll
    for (int off = 32; off > 0; off >>= 1) {
        const float ov = __shfl_down(best, off);
        const int   oi = __shfl_down(bestIdx, off);
        if (ov > best || (ov == best && oi < bestIdx)) { best = ov; bestIdx = oi; }
    }

    __shared__ float sv[4];
    __shared__ int   si[4];
    const int wid  = t >> 6;
    const int lane = t & 63;
    if (lane == 0) { sv[wid] = best; si[wid] = bestIdx; }
    __syncthreads();

    if (t == 0) {
        #pragma unroll
        for (int w = 1; w < 4; ++w) {
            if (sv[w] > best || (sv[w] == best && si[w] < bestIdx)) { best = sv[w]; bestIdx = si[w]; }
        }
        const int x = bestIdx >> 7;     // flat // W  (W == H == 128)
        const int y = bestIdx & 127;    // flat %  W

        float s = 0.0f;
        #pragma unroll
        for (int c = 0; c < NC; ++c) {
            const float z  = pred[(((size_t)b * NC + c) * NH + x) * NW + y];
            const float td = (1.0f - SMOOTHING) * gt[((size_t)b * NJ + j) * NC + c]
                             + SMOOTHING / (float)NC;
            s += fmaxf(z, 0.0f) - z * td + log1pf(expf(-fabsf(z)));
        }
        atomicAdd(&out[b], s * (1.0f / (float)NJ));
    }
}

extern "C" void kernel_launch(void* const* d_in, const int* in_sizes, int n_in,
                              void* d_out, int out_size, void* d_ws, size_t ws_size,
                              hipStream_t stream) {
    const float* pred    = (const float*)d_in[0];
    const float* gt      = (const float*)d_in[1];
    const float* heatmap = (const float*)d_in[2];
    float* out = (float*)d_out;

    // d_out is poisoned by the harness and never re-zeroed between replays.
    hipMemsetAsync(out, 0, (size_t)out_size * sizeof(float), stream);
    labelloss_kernel<<<NB * NJ, 256, 0, stream>>>(pred, gt, heatmap, out);
}

// Round 2
// 30.635 us; speedup vs baseline: 1.5577x; 1.5577x over previous
//
#include <hip/hip_runtime.h>
#include <math.h>

#define NB 32
#define NJ 64
#define NC 7
#define NH 128
#define NW 128
#define HW (NH*NW)
#define SMOOTHING 0.1f

// Kernel 1: one block per (b,j). Argmax over 16384 floats + 7-class smoothed BCE.
// Writes per-object loss (sum over classes) to ws[bj]. No atomics, no memset needed.
__global__ __launch_bounds__(256) void labelloss_scan_kernel(
    const float* __restrict__ pred,
    const float* __restrict__ gt,
    const float* __restrict__ heatmap,
    float* __restrict__ ws)
{
    const int bj = blockIdx.x;          // b*NJ + j
    const int b  = bj >> 6;
    const int j  = bj & 63;
    const float4* __restrict__ hm4 = (const float4*)(heatmap + (size_t)bj * HW);

    const int t = threadIdx.x;
    float best    = -INFINITY;
    int   bestIdx = HW;

    // Per-thread scan visits indices in increasing order, so strict '>' alone
    // preserves first-occurrence argmax semantics (no tie-break compares needed).
    #pragma unroll
    for (int i = 0; i < 16; ++i) {
        const int i4 = t + (i << 8);
        const float4 v = hm4[i4];
        const int base = i4 << 2;
        if (v.x > best) { best = v.x; bestIdx = base;     }
        if (v.y > best) { best = v.y; bestIdx = base + 1; }
        if (v.z > best) { best = v.z; bestIdx = base + 2; }
        if (v.w > best) { best = v.w; bestIdx = base + 3; }
    }

    // Cross-lane: indices unordered -> need (max, tie -> min index).
    #pragma unroll
    for (int off = 32; off > 0; off >>= 1) {
        const float ov = __shfl_down(best, off);
        const int   oi = __shfl_down(bestIdx, off);
        if (ov > best || (ov == best && oi < bestIdx)) { best = ov; bestIdx = oi; }
    }

    __shared__ float sv[4];
    __shared__ int   si[4];
    const int wid  = t >> 6;
    const int lane = t & 63;
    if (lane == 0) { sv[wid] = best; si[wid] = bestIdx; }
    __syncthreads();

    if (t == 0) {
        #pragma unroll
        for (int w = 1; w < 4; ++w) {
            if (sv[w] > best || (sv[w] == best && si[w] < bestIdx)) { best = sv[w]; bestIdx = si[w]; }
        }
        const int x = bestIdx >> 7;     // flat // 128
        const int y = bestIdx & 127;    // flat % 128

        float s = 0.0f;
        #pragma unroll
        for (int c = 0; c < NC; ++c) {
            const float z  = pred[(((size_t)b * NC + c) * NH + x) * NW + y];
            const float td = (1.0f - SMOOTHING) * gt[((size_t)b * NJ + j) * NC + c]
                             + SMOOTHING / (float)NC;
            s += fmaxf(z, 0.0f) - z * td + log1pf(expf(-fabsf(z)));
        }
        ws[bj] = s;
    }
}

// Kernel 2: one wave per b. out[b] = mean_j ws[b*64+j]. Fully overwrites d_out.
__global__ __launch_bounds__(64) void labelloss_reduce_kernel(
    const float* __restrict__ ws,
    float* __restrict__ out)
{
    const int b = blockIdx.x;
    float v = ws[b * NJ + threadIdx.x];
    #pragma unroll
    for (int off = 32; off > 0; off >>= 1) v += __shfl_down(v, off);
    if (threadIdx.x == 0) out[b] = v * (1.0f / (float)NJ);
}

extern "C" void kernel_launch(void* const* d_in, const int* in_sizes, int n_in,
                              void* d_out, int out_size, void* d_ws, size_t ws_size,
                              hipStream_t stream) {
    const float* pred    = (const float*)d_in[0];
    const float* gt      = (const float*)d_in[1];
    const float* heatmap = (const float*)d_in[2];
    float* out = (float*)d_out;
    float* ws  = (float*)d_ws;          // needs NB*NJ*4 = 8 KB

    labelloss_scan_kernel<<<NB * NJ, 256, 0, stream>>>(pred, gt, heatmap, ws);
    labelloss_reduce_kernel<<<NB, 64, 0, stream>>>(ws, out);
}

// Round 3
// 28.531 us; speedup vs baseline: 1.6726x; 1.0738x over previous
//
#include <hip/hip_runtime.h>
#include <math.h>

#define NB 32
#define NJ 64
#define NC 7
#define NH 128
#define NW 128
#define HW (NH*NW)          // 16384 floats per (b,j)
#define SPLIT 2             // half-scans per (b,j)
#define HALF4 (HW/4/SPLIT)  // 2048 float4 per half
#define SMOOTHING 0.1f

// Kernel 1: one block per (b,j,half). Scans 8192 floats (2048 float4, 8/thread),
// writes (maxval, arg flat index) partial to ws. 4096 blocks = 2 generations of
// waves -> early finishers backfill, hiding completion skew.
__global__ __launch_bounds__(256) void labelloss_scan_kernel(
    const float* __restrict__ heatmap,
    float* __restrict__ wsv,
    int*   __restrict__ wsi)
{
    const int blk  = blockIdx.x;        // (b*NJ + j)*SPLIT + half
    const int bj   = blk >> 1;
    const int half = blk & 1;
    const float4* __restrict__ hm4 =
        (const float4*)heatmap + (size_t)bj * (HW/4) + (size_t)half * HALF4;

    const int t = threadIdx.x;
    float best    = -INFINITY;
    int   bestIdx = HW;                 // sentinel

    // Per-thread visit order is increasing -> strict '>' keeps first-occurrence.
    #pragma unroll
    for (int i = 0; i < HALF4/256; ++i) {
        const int i4 = t + (i << 8);
        const float4 v = hm4[i4];
        const int base = (half * HALF4 + i4) << 2;   // flat index within (b,j)
        if (v.x > best) { best = v.x; bestIdx = base;     }
        if (v.y > best) { best = v.y; bestIdx = base + 1; }
        if (v.z > best) { best = v.z; bestIdx = base + 2; }
        if (v.w > best) { best = v.w; bestIdx = base + 3; }
    }

    // wave-64 reduce (max, tie -> min index)
    #pragma unroll
    for (int off = 32; off > 0; off >>= 1) {
        const float ov = __shfl_down(best, off);
        const int   oi = __shfl_down(bestIdx, off);
        if (ov > best || (ov == best && oi < bestIdx)) { best = ov; bestIdx = oi; }
    }

    __shared__ float sv[4];
    __shared__ int   si[4];
    const int wid  = t >> 6;
    const int lane = t & 63;
    if (lane == 0) { sv[wid] = best; si[wid] = bestIdx; }
    __syncthreads();

    if (t == 0) {
        #pragma unroll
        for (int w = 1; w < 4; ++w) {
            if (sv[w] > best || (sv[w] == best && si[w] < bestIdx)) { best = sv[w]; bestIdx = si[w]; }
        }
        wsv[blk] = best;
        wsi[blk] = bestIdx;
    }
}

// Kernel 2: one wave per b. Thread j merges its SPLIT partials, does the
// 7-class smoothed BCE at the argmax location, then wave-reduces the mean.
__global__ __launch_bounds__(64) void labelloss_finish_kernel(
    const float* __restrict__ pred,
    const float* __restrict__ gt,
    const float* __restrict__ wsv,
    const int*   __restrict__ wsi,
    float* __restrict__ out)
{
    const int b = blockIdx.x;
    const int j = threadIdx.x;
    const int p0 = (b * NJ + j) * SPLIT;

    float best    = wsv[p0];
    int   bestIdx = wsi[p0];
    #pragma unroll
    for (int h = 1; h < SPLIT; ++h) {
        const float v = wsv[p0 + h];
        const int   i = wsi[p0 + h];
        if (v > best || (v == best && i < bestIdx)) { best = v; bestIdx = i; }
    }

    const int x = bestIdx >> 7;         // flat // 128
    const int y = bestIdx & 127;        // flat % 128

    float s = 0.0f;
    #pragma unroll
    for (int c = 0; c < NC; ++c) {
        const float z  = pred[(((size_t)b * NC + c) * NH + x) * NW + y];
        const float td = (1.0f - SMOOTHING) * gt[((size_t)b * NJ + j) * NC + c]
                         + SMOOTHING / (float)NC;
        s += fmaxf(z, 0.0f) - z * td + log1pf(expf(-fabsf(z)));
    }

    #pragma unroll
    for (int off = 32; off > 0; off >>= 1) s += __shfl_down(s, off);
    if (j == 0) out[b] = s * (1.0f / (float)NJ);
}

extern "C" void kernel_launch(void* const* d_in, const int* in_sizes, int n_in,
                              void* d_out, int out_size, void* d_ws, size_t ws_size,
                              hipStream_t stream) {
    const float* pred    = (const float*)d_in[0];
    const float* gt      = (const float*)d_in[1];
    const float* heatmap = (const float*)d_in[2];
    float* out = (float*)d_out;
    float* wsv = (float*)d_ws;                          // 4096 floats
    int*   wsi = (int*)((char*)d_ws + NB*NJ*SPLIT*4);   // 4096 ints

    labelloss_scan_kernel<<<NB * NJ * SPLIT, 256, 0, stream>>>(heatmap, wsv, wsi);
    labelloss_finish_kernel<<<NB, 64, 0, stream>>>(pred, gt, wsv, wsi, out);
}